// Round 2
// baseline (11142.270 us; speedup 1.0000x reference)
//
#include <hip/hip_runtime.h>
#include <hip/hip_bf16.h>
#include <stdint.h>

#define SS 4096
#define HH 1024
#define EE 512
#define NB 128
#define SENT 0xFFFFFFFFu

typedef unsigned int u32x4 __attribute__((ext_vector_type(4)));

__device__ __forceinline__ u32x4 ld_coherent_b128(const uint32_t* p) {
  u32x4 r;
  asm volatile("global_load_dwordx4 %0, %1, off sc0 sc1\n\ts_waitcnt vmcnt(0)"
               : "=v"(r) : "v"(p) : "memory");
  return r;
}
__device__ __forceinline__ void st_agent_f32(float* p, float v) {
  __hip_atomic_store(p, v, __ATOMIC_RELAXED, __HIP_MEMORY_SCOPE_AGENT);
}

// x_proj[t][j] = dot(emb[tok[t]], W_in[j]) + b_in[j]
// 64x64 tile per block, K-chunks of 32, 256 threads (16x16, 4x4 microtile).
__global__ __launch_bounds__(256) void xproj_kernel(
    const int* __restrict__ tok, const float* __restrict__ emb,
    const float* __restrict__ Win, const float* __restrict__ bin,
    float* __restrict__ xp)
{
  __shared__ float As[64][33];
  __shared__ float Bs[64][33];
  const int t0 = blockIdx.x * 64;
  const int j0 = blockIdx.y * 64;
  const int tid = threadIdx.x;
  const int lr  = tid >> 3;         // 0..31
  const int lk4 = (tid & 7) << 2;   // 0,4,...,28
  const int tx = tid & 15, ty = tid >> 4;

  const int ta = tok[t0 + lr];
  const int tb = tok[t0 + lr + 32];
  const float* embA = emb + (size_t)ta * EE;
  const float* embB = emb + (size_t)tb * EE;
  const float* winA = Win + (size_t)(j0 + lr) * EE;
  const float* winB = Win + (size_t)(j0 + lr + 32) * EE;

  float acc[4][4];
#pragma unroll
  for (int i = 0; i < 4; ++i)
#pragma unroll
    for (int j = 0; j < 4; ++j) acc[i][j] = 0.f;

  for (int kc = 0; kc < EE; kc += 32) {
    float4 a0 = *(const float4*)(embA + kc + lk4);
    float4 a1 = *(const float4*)(embB + kc + lk4);
    float4 b0 = *(const float4*)(winA + kc + lk4);
    float4 b1 = *(const float4*)(winB + kc + lk4);
    As[lr][lk4 + 0] = a0.x; As[lr][lk4 + 1] = a0.y; As[lr][lk4 + 2] = a0.z; As[lr][lk4 + 3] = a0.w;
    As[lr + 32][lk4 + 0] = a1.x; As[lr + 32][lk4 + 1] = a1.y; As[lr + 32][lk4 + 2] = a1.z; As[lr + 32][lk4 + 3] = a1.w;
    Bs[lr][lk4 + 0] = b0.x; Bs[lr][lk4 + 1] = b0.y; Bs[lr][lk4 + 2] = b0.z; Bs[lr][lk4 + 3] = b0.w;
    Bs[lr + 32][lk4 + 0] = b1.x; Bs[lr + 32][lk4 + 1] = b1.y; Bs[lr + 32][lk4 + 2] = b1.z; Bs[lr + 32][lk4 + 3] = b1.w;
    __syncthreads();
#pragma unroll
    for (int k = 0; k < 32; ++k) {
      float av[4], bv[4];
#pragma unroll
      for (int i = 0; i < 4; ++i) av[i] = As[ty * 4 + i][k];
#pragma unroll
      for (int j = 0; j < 4; ++j) bv[j] = Bs[tx * 4 + j][k];
#pragma unroll
      for (int i = 0; i < 4; ++i)
#pragma unroll
        for (int j = 0; j < 4; ++j) acc[i][j] = fmaf(av[i], bv[j], acc[i][j]);
    }
    __syncthreads();
  }

  float bv[4];
#pragma unroll
  for (int j = 0; j < 4; ++j) bv[j] = bin[j0 + tx * 4 + j];
#pragma unroll
  for (int i = 0; i < 4; ++i) {
    float4 o;
    o.x = acc[i][0] + bv[0]; o.y = acc[i][1] + bv[1];
    o.z = acc[i][2] + bv[2]; o.w = acc[i][3] + bv[3];
    *(float4*)(xp + (size_t)(t0 + ty * 4 + i) * HH + j0 + tx * 4) = o;
  }
}

// Persistent recurrence: 128 blocks x 256 threads. Block b owns rows
// [8b, 8b+8); wave w computes rows 8b+2w, 8b+2w+1. Lane l holds
// W_h[row][c*256 + 4l + j] for c=0..3, j=0..3 (32 regs/thread total).
// hist slot t holds h_{t+1}; values double as ready-flags (sentinel
// 0xFFFFFFFF = NaN, impossible for a tanh output). Per step, wave w
// polls ONLY quarter w of h with one coherent dwordx4 per lane (the
// winning poll load IS the data), shares it via double-buffered LDS,
// then all waves read their fragments from LDS. This cuts coherent
// poll traffic 4x in bytes and 16x in requests vs all-waves-poll-all.
__global__ __launch_bounds__(256) void rnn_kernel(
    const float* __restrict__ Wh, const float* __restrict__ bh,
    const float* __restrict__ xp, float* __restrict__ hist,
    const float* __restrict__ Wout, const float* __restrict__ bout,
    float* __restrict__ out)
{
  __shared__ float hsh[2][HH];
  const int blk = blockIdx.x;
  const int tid = threadIdx.x;
  const int w = tid >> 6;
  const int l = tid & 63;
  const int rowA = blk * 8 + 2 * w;
  const int rowB = rowA + 1;

  // Weight fragments: wa4[c] = W_h[rowA][c*256 + 4l .. 4l+3]
  float4 wa4[4], wb4[4];
#pragma unroll
  for (int c = 0; c < 4; ++c) {
    wa4[c] = *(const float4*)(Wh + (size_t)rowA * HH + (c << 8) + (l << 2));
    wb4[c] = *(const float4*)(Wh + (size_t)rowB * HH + (c << 8) + (l << 2));
  }
  const float bhA = bh[rowA];
  const float bhB = bh[rowB];

  for (int t = 0; t < SS; ++t) {
    float xA = xp[(size_t)t * HH + rowA];   // issued before poll; cheap L2/L3 hit
    float xB = xp[(size_t)t * HH + rowB];
    float acc0 = 0.f, acc1 = 0.f;
    if (t > 0) {
      const uint32_t* hs = (const uint32_t*)(hist + (size_t)(t - 1) * HH);
      const uint32_t* q = hs + (w << 8) + (l << 2);   // wave w's quarter
      u32x4 r;
      for (;;) {
        r = ld_coherent_b128(q);
        int ok = (r[0] != SENT) & (r[1] != SENT) & (r[2] != SENT) & (r[3] != SENT);
        if (__all(ok)) break;
      }
      // Share quarter via LDS (double-buffered by t parity: one barrier/step).
      *(u32x4*)&hsh[t & 1][(w << 8) + (l << 2)] = r;
      __syncthreads();
      float4 pa, pb;
      pa.x = pa.y = pa.z = pa.w = 0.f;
      pb.x = pb.y = pb.z = pb.w = 0.f;
#pragma unroll
      for (int c = 0; c < 4; ++c) {
        float4 h4 = *(const float4*)&hsh[t & 1][(c << 8) + (l << 2)];
        pa.x = fmaf(wa4[c].x, h4.x, pa.x); pa.y = fmaf(wa4[c].y, h4.y, pa.y);
        pa.z = fmaf(wa4[c].z, h4.z, pa.z); pa.w = fmaf(wa4[c].w, h4.w, pa.w);
        pb.x = fmaf(wb4[c].x, h4.x, pb.x); pb.y = fmaf(wb4[c].y, h4.y, pb.y);
        pb.z = fmaf(wb4[c].z, h4.z, pb.z); pb.w = fmaf(wb4[c].w, h4.w, pb.w);
      }
      acc0 = (pa.x + pa.y) + (pa.z + pa.w);
      acc1 = (pb.x + pb.y) + (pb.z + pb.w);
    }
#pragma unroll
    for (int off = 1; off < 64; off <<= 1) {
      acc0 += __shfl_xor(acc0, off);
      acc1 += __shfl_xor(acc1, off);
    }
    if (l < 2) {
      float pre = (l == 0) ? (acc0 + xA + bhA) : (acc1 + xB + bhB);
      float hval = tanhf(pre);
      st_agent_f32(hist + (size_t)t * HH + rowA + l, hval);
    }
  }

  // Epilogue: block 0, wave 0 computes the classifier head + log_softmax.
  if (blk == 0 && w == 0) {
    const uint32_t* hs = (const uint32_t*)(hist + (size_t)(SS - 1) * HH);
    u32x4 hv[4];
    for (;;) {
      int ok = 1;
#pragma unroll
      for (int c = 0; c < 4; ++c) {
        hv[c] = ld_coherent_b128(hs + (c << 8) + (l << 2));
        ok &= (hv[c][0] != SENT) & (hv[c][1] != SENT) &
              (hv[c][2] != SENT) & (hv[c][3] != SENT);
      }
      if (__all(ok)) break;
    }
    float c0 = 0.f, c1 = 0.f;
#pragma unroll
    for (int c = 0; c < 4; ++c) {
#pragma unroll
      for (int j = 0; j < 4; ++j) {
        float h = __uint_as_float(hv[c][j]);
        int col = (c << 8) + (l << 2) + j;
        c0 = fmaf(Wout[col], h, c0);
        c1 = fmaf(Wout[HH + col], h, c1);
      }
    }
#pragma unroll
    for (int off = 1; off < 64; off <<= 1) {
      c0 += __shfl_xor(c0, off);
      c1 += __shfl_xor(c1, off);
    }
    if (l == 0) {
      float s0 = c0 + bout[0];
      float s1 = c1 + bout[1];
      float m = fmaxf(s0, s1);
      float lse = m + logf(expf(s0 - m) + expf(s1 - m));
      out[0] = s0 - lse;
      out[1] = s1 - lse;
    }
  }
}

extern "C" void kernel_launch(void* const* d_in, const int* in_sizes, int n_in,
                              void* d_out, int out_size, void* d_ws, size_t ws_size,
                              hipStream_t stream)
{
  const int*   tok  = (const int*)  d_in[0];
  const float* emb  = (const float*)d_in[1];
  const float* Win  = (const float*)d_in[2];
  const float* bin  = (const float*)d_in[3];
  const float* Wh   = (const float*)d_in[4];
  const float* bh   = (const float*)d_in[5];
  const float* Wout = (const float*)d_in[6];
  const float* bout = (const float*)d_in[7];

  const size_t need = (size_t)2 * SS * HH * sizeof(float);  // xp + hist = 32 MB
  if (ws_size < need) return;

  float* xp   = (float*)d_ws;
  float* hist = xp + (size_t)SS * HH;

  // Sentinel-fill the h history each launch (0xFF bytes = NaN = "not written").
  hipMemsetAsync(hist, 0xFF, (size_t)SS * HH * sizeof(float), stream);

  xproj_kernel<<<dim3(SS / 64, HH / 64), 256, 0, stream>>>(tok, emb, Win, bin, xp);
  rnn_kernel<<<NB, 256, 0, stream>>>(Wh, bh, xp, hist, Wout, bout, (float*)d_out);
}

// Round 4
// 8289.906 us; speedup vs baseline: 1.3441x; 1.3441x over previous
//
#include <hip/hip_runtime.h>
#include <hip/hip_bf16.h>
#include <stdint.h>

#define SS 4096
#define HH 1024
#define EE 512
#define NBLK 64
#define SENT 0xFFFFFFFFu

typedef unsigned int u32x4 __attribute__((ext_vector_type(4)));

// x_proj[t][j] = dot(emb[tok[t]], W_in[j]) + b_in[j]  (proven, ~70us)
__global__ __launch_bounds__(256) void xproj_kernel(
    const int* __restrict__ tok, const float* __restrict__ emb,
    const float* __restrict__ Win, const float* __restrict__ bin,
    float* __restrict__ xp)
{
  __shared__ float As[64][33];
  __shared__ float Bs[64][33];
  const int t0 = blockIdx.x * 64;
  const int j0 = blockIdx.y * 64;
  const int tid = threadIdx.x;
  const int lr  = tid >> 3;
  const int lk4 = (tid & 7) << 2;
  const int tx = tid & 15, ty = tid >> 4;

  const int ta = tok[t0 + lr];
  const int tb = tok[t0 + lr + 32];
  const float* embA = emb + (size_t)ta * EE;
  const float* embB = emb + (size_t)tb * EE;
  const float* winA = Win + (size_t)(j0 + lr) * EE;
  const float* winB = Win + (size_t)(j0 + lr + 32) * EE;

  float acc[4][4];
#pragma unroll
  for (int i = 0; i < 4; ++i)
#pragma unroll
    for (int j = 0; j < 4; ++j) acc[i][j] = 0.f;

  for (int kc = 0; kc < EE; kc += 32) {
    float4 a0 = *(const float4*)(embA + kc + lk4);
    float4 a1 = *(const float4*)(embB + kc + lk4);
    float4 b0 = *(const float4*)(winA + kc + lk4);
    float4 b1 = *(const float4*)(winB + kc + lk4);
    As[lr][lk4 + 0] = a0.x; As[lr][lk4 + 1] = a0.y; As[lr][lk4 + 2] = a0.z; As[lr][lk4 + 3] = a0.w;
    As[lr + 32][lk4 + 0] = a1.x; As[lr + 32][lk4 + 1] = a1.y; As[lr + 32][lk4 + 2] = a1.z; As[lr + 32][lk4 + 3] = a1.w;
    Bs[lr][lk4 + 0] = b0.x; Bs[lr][lk4 + 1] = b0.y; Bs[lr][lk4 + 2] = b0.z; Bs[lr][lk4 + 3] = b0.w;
    Bs[lr + 32][lk4 + 0] = b1.x; Bs[lr + 32][lk4 + 1] = b1.y; Bs[lr + 32][lk4 + 2] = b1.z; Bs[lr + 32][lk4 + 3] = b1.w;
    __syncthreads();
#pragma unroll
    for (int k = 0; k < 32; ++k) {
      float av[4], bv[4];
#pragma unroll
      for (int i = 0; i < 4; ++i) av[i] = As[ty * 4 + i][k];
#pragma unroll
      for (int j = 0; j < 4; ++j) bv[j] = Bs[tx * 4 + j][k];
#pragma unroll
      for (int i = 0; i < 4; ++i)
#pragma unroll
        for (int j = 0; j < 4; ++j) acc[i][j] = fmaf(av[i], bv[j], acc[i][j]);
    }
    __syncthreads();
  }

  float bv[4];
#pragma unroll
  for (int j = 0; j < 4; ++j) bv[j] = bin[j0 + tx * 4 + j];
#pragma unroll
  for (int i = 0; i < 4; ++i) {
    float4 o;
    o.x = acc[i][0] + bv[0]; o.y = acc[i][1] + bv[1];
    o.z = acc[i][2] + bv[2]; o.w = acc[i][3] + bv[3];
    *(float4*)(xp + (size_t)(t0 + ty * 4 + i) * HH + j0 + tx * 4) = o;
  }
}

// Persistent recurrence, device-scope (agent) communication via IF.
// 64 blocks x 256 threads. Block b owns rows [16b,16b+16); wave w computes
// rows 16b+4w..16b+4w+3; lane l holds W_h[row][c*256+4l..4l+3], c=0..3
// (64 weight VGPRs). Per step: wave w polls ONLY quarter w of h with one
// agent-scope (sc1) dwordx4 — the winning poll load IS the data — shares
// via double-buffered LDS (one barrier), FMAs, reduces, and stores its 4
// rows with one 4-lane coalesced sc1 store. Poll traffic: 256 requests /
// 256 KB per iteration vs round-1's 8192 / 2 MB. Sentinel 0xFFFFFFFF
// (negative NaN) can never be produced by tanhf. Deadlock-free by
// induction (no block waits on anything produced later than step t-1;
// all 64 blocks trivially co-resident).
__global__ __launch_bounds__(256) void rnn_kernel(
    const float* __restrict__ Wh, const float* __restrict__ bh,
    const float* __restrict__ xp, float* __restrict__ hist,
    const float* __restrict__ Wout, const float* __restrict__ bout,
    float* __restrict__ out)
{
  __shared__ float hsh[2][HH];
  const int blk = blockIdx.x;
  const int tid = threadIdx.x;
  const int w = tid >> 6, l = tid & 63;
  const int r0 = blk * 16 + w * 4;        // wave's first row
  const int myrow = r0 + (l & 3);         // row this lane finalizes

  // Weights: wv[r][c] = W_h[r0+r][c*256 + 4l .. 4l+3]
  float4 wv[4][4];
#pragma unroll
  for (int r = 0; r < 4; ++r)
#pragma unroll
    for (int c = 0; c < 4; ++c)
      wv[r][c] = *(const float4*)(Wh + (size_t)(r0 + r) * HH + (c << 8) + (l << 2));
  const float bhv = bh[myrow];

  for (int t = 0; t < SS; ++t) {
    const float xv = xp[(size_t)t * HH + myrow];  // plain load, L2-warm
    float a0 = 0.f, a1 = 0.f, a2 = 0.f, a3 = 0.f;
    if (t > 0) {
      const uint32_t* q = (const uint32_t*)(hist + (size_t)(t - 1) * HH)
                          + (w << 8) + (l << 2);
      u32x4 r;
      for (;;) {
        asm volatile("global_load_dwordx4 %0, %1, off sc1\n\ts_waitcnt vmcnt(0)"
                     : "=&v"(r) : "v"(q) : "memory");
        int ok = (r[0] != SENT) & (r[1] != SENT) & (r[2] != SENT) & (r[3] != SENT);
        if (__all(ok)) break;
      }
      *(u32x4*)&hsh[t & 1][(w << 8) + (l << 2)] = r;
      __syncthreads();
#pragma unroll
      for (int c = 0; c < 4; ++c) {
        float4 h4 = *(const float4*)&hsh[t & 1][(c << 8) + (l << 2)];
        a0 = fmaf(wv[0][c].x, h4.x, a0); a0 = fmaf(wv[0][c].y, h4.y, a0);
        a0 = fmaf(wv[0][c].z, h4.z, a0); a0 = fmaf(wv[0][c].w, h4.w, a0);
        a1 = fmaf(wv[1][c].x, h4.x, a1); a1 = fmaf(wv[1][c].y, h4.y, a1);
        a1 = fmaf(wv[1][c].z, h4.z, a1); a1 = fmaf(wv[1][c].w, h4.w, a1);
        a2 = fmaf(wv[2][c].x, h4.x, a2); a2 = fmaf(wv[2][c].y, h4.y, a2);
        a2 = fmaf(wv[2][c].z, h4.z, a2); a2 = fmaf(wv[2][c].w, h4.w, a2);
        a3 = fmaf(wv[3][c].x, h4.x, a3); a3 = fmaf(wv[3][c].y, h4.y, a3);
        a3 = fmaf(wv[3][c].z, h4.z, a3); a3 = fmaf(wv[3][c].w, h4.w, a3);
      }
    }
    // Reduce: phase 1, full xor-add over lane bits 2..5.
#pragma unroll
    for (int off = 4; off <= 32; off <<= 1) {
      a0 += __shfl_xor(a0, off);
      a1 += __shfl_xor(a1, off);
      a2 += __shfl_xor(a2, off);
      a3 += __shfl_xor(a3, off);
    }
    // Phase 2: halving merges over bits 0,1; lane l ends with row (l&3).
    const bool b0 = (l & 1), b1 = (l & 2);
    float c01 = (b0 ? a1 : a0) + __shfl_xor(b0 ? a0 : a1, 1);
    float c23 = (b0 ? a3 : a2) + __shfl_xor(b0 ? a2 : a3, 1);
    float S   = (b1 ? c23 : c01) + __shfl_xor(b1 ? c01 : c23, 2);

    const float hval = tanhf(S + xv + bhv);
    if (l < 4) {
      float* addr = hist + (size_t)t * HH + r0 + l;  // 4 lanes, 16B coalesced
      asm volatile("global_store_dword %0, %1, off sc1"
                   :: "v"(addr), "v"(hval) : "memory");
    }
  }

  // Epilogue: block 0, wave 0 computes the classifier head + log_softmax.
  if (blk == 0 && w == 0) {
    const uint32_t* hs = (const uint32_t*)(hist + (size_t)(SS - 1) * HH) + (l << 2);
    u32x4 h4[4];
    for (;;) {
      asm volatile(
          "global_load_dwordx4 %0, %4, off sc1\n\t"
          "global_load_dwordx4 %1, %4, off offset:1024 sc1\n\t"
          "global_load_dwordx4 %2, %4, off offset:2048 sc1\n\t"
          "global_load_dwordx4 %3, %4, off offset:3072 sc1\n\t"
          "s_waitcnt vmcnt(0)"
          : "=&v"(h4[0]), "=&v"(h4[1]), "=&v"(h4[2]), "=&v"(h4[3])
          : "v"(hs) : "memory");
      int ok = 1;
#pragma unroll
      for (int c = 0; c < 4; ++c)
        ok &= (h4[c][0] != SENT) & (h4[c][1] != SENT) &
              (h4[c][2] != SENT) & (h4[c][3] != SENT);
      if (__all(ok)) break;
    }
    float c0 = 0.f, c1 = 0.f;
#pragma unroll
    for (int c = 0; c < 4; ++c)
#pragma unroll
      for (int j = 0; j < 4; ++j) {
        float h = __uint_as_float(h4[c][j]);
        int col = (c << 8) + (l << 2) + j;
        c0 = fmaf(Wout[col], h, c0);
        c1 = fmaf(Wout[HH + col], h, c1);
      }
#pragma unroll
    for (int off = 1; off < 64; off <<= 1) {
      c0 += __shfl_xor(c0, off);
      c1 += __shfl_xor(c1, off);
    }
    if (l == 0) {
      float s0 = c0 + bout[0];
      float s1 = c1 + bout[1];
      float m = fmaxf(s0, s1);
      float lse = m + logf(expf(s0 - m) + expf(s1 - m));
      out[0] = s0 - lse;
      out[1] = s1 - lse;
    }
  }
}

extern "C" void kernel_launch(void* const* d_in, const int* in_sizes, int n_in,
                              void* d_out, int out_size, void* d_ws, size_t ws_size,
                              hipStream_t stream)
{
  const int*   tok  = (const int*)  d_in[0];
  const float* emb  = (const float*)d_in[1];
  const float* Win  = (const float*)d_in[2];
  const float* bin  = (const float*)d_in[3];
  const float* Wh   = (const float*)d_in[4];
  const float* bh   = (const float*)d_in[5];
  const float* Wout = (const float*)d_in[6];
  const float* bout = (const float*)d_in[7];

  const size_t need = (size_t)2 * SS * HH * sizeof(float);  // xp + hist = 32MB
  if (ws_size < need) return;

  float* xp   = (float*)d_ws;
  float* hist = xp + (size_t)SS * HH;

  // Sentinel-fill h history each launch (0xFF bytes = negative NaN = "unwritten").
  hipMemsetAsync(hist, 0xFF, (size_t)SS * HH * sizeof(float), stream);

  xproj_kernel<<<dim3(SS / 64, HH / 64), 256, 0, stream>>>(tok, emb, Win, bin, xp);
  rnn_kernel<<<NBLK, 256, 0, stream>>>(Wh, bh, xp, hist, Wout, bout, (float*)d_out);
}